// Round 9
// baseline (89.685 us; speedup 1.0000x reference)
//
#include <hip/hip_runtime.h>
#include <math.h>

#define BB 16
#define NN 2048
#define MM 16
#define SS 128

__constant__ const float kFourPi = 12.566370614359172f;

// ---------------------------------------------------------------------------
// Kernel A: one block per (b,m), 1024 threads (16 waves), 1 block/CU.
// Register-safe d2 path: s-loop split into two halves of 16; d2r[16] folded
// to LDS right after each half (peak live regs ~75 << 128 cap -> no spill).
// Fold: masks 32,16,8,4 move s-bits[3:0] into lane-bits[5:2]; xor2/xor1
// complete the 64-lane min (each s duplicated x4; epilogue reads lane 4*k).
// ---------------------------------------------------------------------------
__global__ __launch_bounds__(1024, 4) void fused_dist_kernel(
    const float* __restrict__ pcl,    // (B,N,M,3)
    const float* __restrict__ prim,   // (B,M,S,3)
    float* __restrict__ d1,           // [256][2048]  (e-scale, e = d/2)
    float* __restrict__ d2sum,        // [256]        (d-scale)
    unsigned int* __restrict__ counter)
{
    const int bm  = blockIdx.x;
    const int b   = bm >> 4;
    const int m   = bm & 15;
    const int tid = threadIdx.x;

    __shared__ float  Qx[NN], Qy[NN], Qz[NN], Qh[NN];  // 32 KB
    __shared__ float4 Plds[SS];                        // 2 KB (x,y,z,hp)
    __shared__ float  d1s[4][NN];                      // 32 KB
    __shared__ float  wredA[16][64];                   // 4 KB (half 0)
    __shared__ float  wredB[16][64];                   // 4 KB (half 1)
    __shared__ float  rsum[2];

    if (bm == 0 && tid == 0)
        __hip_atomic_store(counter, 0u, __ATOMIC_RELAXED, __HIP_MEMORY_SCOPE_AGENT);

    // stage pcl[b,:,m,:] (12B-of-192B scatter, read exactly once) + 0.5|q|^2
    {
        const size_t base = ((size_t)(b * NN) * MM + m) * 3;
#pragma unroll
        for (int j = 0; j < 2; ++j) {
            const int n = tid + j * 1024;
            const float* q = pcl + base + (size_t)n * (MM * 3);
            const float x = q[0], y = q[1], z = q[2];
            Qx[n] = x; Qy[n] = y; Qz[n] = z;
            Qh[n] = 0.5f * (x * x + y * y + z * z);
        }
    }
    if (tid < SS) {
        const float* pp = prim + ((size_t)bm * SS + tid) * 3;
        const float x = pp[0], y = pp[1], z = pp[2];
        Plds[tid] = make_float4(x, y, z, 0.5f * (x * x + y * y + z * z));
    }
    __syncthreads();

    const int sub  = tid >> 8;    // s-chunk 0..3 (32 s each)
    const int stid = tid & 255;
    const int s0   = sub * 32;
    const int wid  = tid >> 6;    // 0..15
    const int lane = tid & 63;

    float qx[8], qy[8], qz[8], hq[8], d1m[8];
#pragma unroll
    for (int j = 0; j < 8; ++j) {
        const int n = stid + j * 256;
        qx[j] = Qx[n]; qy[j] = Qy[n]; qz[j] = Qz[n]; hq[j] = Qh[n];
        d1m[j] = 3.0e38f;
    }

    // two halves of 16 s; fold each half's d2r[16] immediately (low reg peak)
#pragma unroll
    for (int h = 0; h < 2; ++h) {
        float d2r[16];
#pragma unroll
        for (int s = 0; s < 16; ++s) {
            const float4 f = Plds[s0 + h * 16 + s];   // wave-uniform ds_read_b128
            float e[8];
#pragma unroll
            for (int j = 0; j < 8; ++j) {
                float t = hq[j] + f.w;                // 0.5|q|^2 + 0.5|p|^2
                t = fmaf(f.x, -qx[j], t);
                t = fmaf(f.y, -qy[j], t);
                t = fmaf(f.z, -qz[j], t);
                e[j] = t;
                d1m[j] = fminf(d1m[j], t);
            }
            const float m01 = fminf(e[0], e[1]);
            const float m23 = fminf(e[2], e[3]);
            const float m45 = fminf(e[4], e[5]);
            const float m67 = fminf(e[6], e[7]);
            d2r[s] = fminf(fminf(m01, m23), fminf(m45, m67));
        }

        // fold 16 values over 64 lanes: s-bits[3:0] -> lane-bits[5:2]
        float v8[8];
        {
            const bool hi = (lane & 32) != 0;
#pragma unroll
            for (int k = 0; k < 8; ++k) {
                const float xk = hi ? d2r[k + 8] : d2r[k];
                const float xs = hi ? d2r[k] : d2r[k + 8];
                v8[k] = fminf(xk, __shfl_xor(xs, 32, 64));
            }
        }
        float v4[4];
        {
            const bool hi = (lane & 16) != 0;
#pragma unroll
            for (int k = 0; k < 4; ++k) {
                const float xk = hi ? v8[k + 4] : v8[k];
                const float xs = hi ? v8[k] : v8[k + 4];
                v4[k] = fminf(xk, __shfl_xor(xs, 16, 64));
            }
        }
        float v2a, v2b;
        {
            const bool hi = (lane & 8) != 0;
            const float xk0 = hi ? v4[2] : v4[0];
            const float xs0 = hi ? v4[0] : v4[2];
            v2a = fminf(xk0, __shfl_xor(xs0, 8, 64));
            const float xk1 = hi ? v4[3] : v4[1];
            const float xs1 = hi ? v4[1] : v4[3];
            v2b = fminf(xk1, __shfl_xor(xs1, 8, 64));
        }
        float v1;
        {
            const bool hi = (lane & 4) != 0;
            const float xk = hi ? v2b : v2a;
            const float xs = hi ? v2a : v2b;
            v1 = fminf(xk, __shfl_xor(xs, 4, 64));
        }
        // complete 64-lane min (s_local = lane bits[5:2], dup x4)
        v1 = fminf(v1, __shfl_xor(v1, 2, 64));
        v1 = fminf(v1, __shfl_xor(v1, 1, 64));
        if (h == 0) wredA[wid][lane] = v1;
        else        wredB[wid][lane] = v1;
    }

    // d1: combine 4 s-chunks in LDS, coalesced e-scale global write
#pragma unroll
    for (int j = 0; j < 8; ++j)
        d1s[sub][stid + j * 256] = d1m[j];
    __syncthreads();
#pragma unroll
    for (int j = 0; j < 2; ++j) {
        const int n = tid + j * 1024;
        d1[(size_t)bm * NN + n] = fminf(fminf(d1s[0][n], d1s[1][n]),
                                        fminf(d1s[2][n], d1s[3][n]));
    }

    // d2 epilogue: tid<128 handles s=tid; min over the s-chunk's 4 waves.
    if (tid < 128) {                    // waves 0,1 fully active
        const int s    = tid;
        const int ssub = s >> 5;        // which 32-s chunk
        const int sh   = (s >> 4) & 1;  // which half
        const int k    = s & 15;        // s_local within half
        const int l4   = k * 4;         // representative lane (dup x4)
        const int w0   = ssub * 4;
        float v;
        if (sh == 0)
            v = fminf(fminf(wredA[w0 + 0][l4], wredA[w0 + 1][l4]),
                      fminf(wredA[w0 + 2][l4], wredA[w0 + 3][l4]));
        else
            v = fminf(fminf(wredB[w0 + 0][l4], wredB[w0 + 1][l4]),
                      fminf(wredB[w0 + 2][l4], wredB[w0 + 3][l4]));
        if (v >= 5.0e29f) v = 0.0f;     // clamp at e-scale (d >= 1e30)
#pragma unroll
        for (int off = 32; off > 0; off >>= 1)
            v += __shfl_down(v, off, 64);
        if (lane == 0) rsum[wid] = v;
    }
    __syncthreads();
    if (tid == 0) d2sum[bm] = 2.0f * (rsum[0] + rsum[1]);   // e -> d
}

// ---------------------------------------------------------------------------
// Kernel B: p2p sort + stick-breaking; last block finalizes.
// grid 128 x 256; one thread per (b,n).
// ---------------------------------------------------------------------------
__global__ __launch_bounds__(256) void p2p_final_kernel(
    const float* __restrict__ d1,      // [256][2048] (e-scale)
    const float* __restrict__ probs,   // (B,M)
    const float* __restrict__ size_,   // (B,M,3)
    const float* __restrict__ d2sum,   // [256]
    float* __restrict__ partial,       // [128]
    unsigned int* __restrict__ counter,
    float* __restrict__ out)           // (4)
{
    const int tid = threadIdx.x;
    const int gid = blockIdx.x * 256 + tid;   // b*N + n
    const int b   = gid >> 11;
    const int n   = gid & (NN - 1);

    float d[16], p[16];
#pragma unroll
    for (int m = 0; m < 16; ++m) {
        const float mn = d1[((size_t)(b * MM + m)) * NN + n];
        d[m] = mn + mn;                       // e -> d
    }

    const float* pb = probs + b * MM;
#pragma unroll
    for (int k = 0; k < 16; ++k) p[k] = pb[k];

#define CE(i, j)                                              \
    {                                                         \
        const bool c = d[i] > d[j];                           \
        const float td = c ? d[j] : d[i];                     \
        d[j] = c ? d[i] : d[j];  d[i] = td;                   \
        const float tp = c ? p[j] : p[i];                     \
        p[j] = c ? p[i] : p[j];  p[i] = tp;                   \
    }
#pragma unroll
    for (int r = 0; r < 16; ++r) {
        if ((r & 1) == 0) {
            CE(0, 1) CE(2, 3) CE(4, 5) CE(6, 7)
            CE(8, 9) CE(10, 11) CE(12, 13) CE(14, 15)
        } else {
            CE(1, 2) CE(3, 4) CE(5, 6) CE(7, 8)
            CE(9, 10) CE(11, 12) CE(13, 14)
        }
    }
#undef CE

    float acc = 1.0f, sum = 0.0f;
#pragma unroll
    for (int k = 0; k < 16; ++k) {
        sum += d[k] * p[k] * acc;
        acc *= (1.0f - p[k]);
    }

    const int wid  = tid >> 6;
    const int lane = tid & 63;
    __shared__ float red4[4];
#pragma unroll
    for (int off = 32; off > 0; off >>= 1)
        sum += __shfl_down(sum, off, 64);
    if (lane == 0) red4[wid] = sum;
    __syncthreads();

    __shared__ bool amLast;
    if (tid == 0) {
        const float bsum = red4[0] + red4[1] + red4[2] + red4[3];
        __hip_atomic_store(&partial[blockIdx.x], bsum,
                           __ATOMIC_RELEASE, __HIP_MEMORY_SCOPE_AGENT);
        const unsigned int prev = __hip_atomic_fetch_add(
            counter, 1u, __ATOMIC_ACQ_REL, __HIP_MEMORY_SCOPE_AGENT);
        amLast = (prev == 127u);
    }
    __syncthreads();
    if (!amLast) return;

    // ---- finalize (one block; tid == b*16 + m) ----
    const int fb = tid >> 4;

    __shared__ float  areaSh[256];
    __shared__ double redA[4];
    __shared__ double redB[4];

    const float s0 = size_[tid * 3 + 0];
    const float s1 = size_[tid * 3 + 1];
    const float s2 = size_[tid * 3 + 2];
    const float inner = powf(s0 * s1, 1.6f) * (1.0f / 3.0f)
                      + powf(s0 * s2, 1.6f) * (1.0f / 3.0f)
                      + powf(s1 * s2, 1.6f) * (1.0f / 3.0f);
    const float a = kFourPi * powf(inner, 0.625f);
    areaSh[tid] = a;
    __syncthreads();

    float asum = 0.0f;
#pragma unroll
    for (int mm = 0; mm < 16; ++mm) asum += areaSh[fb * 16 + mm];
    const float anorm = 16.0f * a / asum;   // M * area / sum_m area

    double t = (double)(d2sum[tid] * (1.0f / 128.0f)) * (double)probs[tid] * (double)anorm;
#pragma unroll
    for (int off = 32; off > 0; off >>= 1)
        t += __shfl_down(t, off, 64);
    if (lane == 0) redA[wid] = t;

    double u = 0.0;
    if (tid < 128) {
        const float pv = __hip_atomic_load(&partial[tid],
                                           __ATOMIC_ACQUIRE, __HIP_MEMORY_SCOPE_AGENT);
        u = (double)pv;
    }
#pragma unroll
    for (int off = 32; off > 0; off >>= 1)
        u += __shfl_down(u, off, 64);
    if (lane == 0) redB[wid] = u;

    __syncthreads();
    if (tid == 0) {
        const double prim_to_pcl = (redA[0] + redA[1] + redA[2] + redA[3]) / 256.0;    // /(B*M)
        const double pcl_to_prim = (redB[0] + redB[1] + redB[2] + redB[3]) / 32768.0;  // /(B*N)
        out[0] = (float)(pcl_to_prim + prim_to_pcl);
        out[1] = (float)pcl_to_prim;
        out[2] = (float)prim_to_pcl;
        out[3] = 0.0f;
    }
}

// ---------------------------------------------------------------------------

extern "C" void kernel_launch(void* const* d_in, const int* in_sizes, int n_in,
                              void* d_out, int out_size, void* d_ws, size_t ws_size,
                              hipStream_t stream) {
    const float* pcl   = (const float*)d_in[0];  // (B,N,M,3)
    const float* prim  = (const float*)d_in[1];  // (B,M,S,3)
    const float* size_ = (const float*)d_in[2];  // (B,M,3)
    const float* probs = (const float*)d_in[3];  // (B,M)
    float* out = (float*)d_out;

    float* d1             = (float*)d_ws;             // 256*2048 floats (2 MiB)
    float* d2sum          = d1 + (size_t)256 * NN;    // 256
    float* partial        = d2sum + 256;              // 128
    unsigned int* counter = (unsigned int*)(partial + 128);

    fused_dist_kernel<<<BB * MM, 1024, 0, stream>>>(pcl, prim, d1, d2sum, counter);
    p2p_final_kernel<<<128, 256, 0, stream>>>(d1, probs, size_, d2sum, partial, counter, out);
}